// Round 5
// baseline (716.246 us; speedup 1.0000x reference)
//
#include <hip/hip_runtime.h>

// RISnetPIv2: B=128, U=16, A=1024, FEAT=4, INFO=8.
// e_u/e_a uniform averaging -> 32-ch feature factors into ll[B,U,A,8] (bf16),
// lg[B,U,8], gl[B,A,8], gg[B,8] (fp32).
// Round-5: CHANNEL-SPLIT. Cross-round law: dur ~ 1/occupancy ~ VGPR; packed
// math (r4) halved issue but VGPR 52->72 lost it. Fix: split the 32 output
// channels over two wave-uniform groups (tid>>7): group0 = ll+lg (ch 0-15),
// group1 = gl+gg (ch 16-31). Per-thread y2[8]+cgl2[8] (32 VGPR total state
// vs 64), conv 64 pk_fma/u, u-loop 8 (NZ=2 -> gl traffic halved, cgl
// amortized 2x). Groups race on in-place ll -> run NON-in-place (A->B
// ping-pong + pinned f3s; ws need == old NZ=4 need exactly). Barrier-synced
// in-place fallback for smaller ws.

#define NB 128
#define NU 16
#define NA 1024

typedef float v2f __attribute__((ext_vector_type(2)));

static constexpr float PI_F = 3.14159265358979323846f;

__device__ __forceinline__ void unpack8(uint4 v, float x[8]) {
    x[0] = __uint_as_float(v.x << 16); x[1] = __uint_as_float(v.x & 0xffff0000u);
    x[2] = __uint_as_float(v.y << 16); x[3] = __uint_as_float(v.y & 0xffff0000u);
    x[4] = __uint_as_float(v.z << 16); x[5] = __uint_as_float(v.z & 0xffff0000u);
    x[6] = __uint_as_float(v.w << 16); x[7] = __uint_as_float(v.w & 0xffff0000u);
}
__device__ __forceinline__ void unpack8v(uint4 v, v2f x2[4]) {
    x2[0] = v2f{__uint_as_float(v.x << 16), __uint_as_float(v.x & 0xffff0000u)};
    x2[1] = v2f{__uint_as_float(v.y << 16), __uint_as_float(v.y & 0xffff0000u)};
    x2[2] = v2f{__uint_as_float(v.z << 16), __uint_as_float(v.z & 0xffff0000u)};
    x2[3] = v2f{__uint_as_float(v.w << 16), __uint_as_float(v.w & 0xffff0000u)};
}
__device__ __forceinline__ unsigned int cvtpk(float a, float b) {
    unsigned int r;
    asm("v_cvt_pk_bf16_f32 %0, %1, %2" : "=v"(r) : "v"(a), "v"(b));
    return r;  // lo = bf16(a), hi = bf16(b), RNE
}
__device__ __forceinline__ void store8v(unsigned short* p, const v2f y2[4]) {
    uint4 v;
    v.x = cvtpk(y2[0].x, y2[0].y); v.y = cvtpk(y2[1].x, y2[1].y);
    v.z = cvtpk(y2[2].x, y2[2].y); v.w = cvtpk(y2[3].x, y2[3].y);
    *reinterpret_cast<uint4*>(p) = v;
}

// Full-wave per-channel sum: input v[0..7] per lane; output = wave sum of
// channel (lane&7), replicated across lanes (10 shuffles). Proven r2.
__device__ __forceinline__ float chan_reduce8(const float* v, int lane) {
    float w[4];
    const bool s0 = (lane & 1) != 0;
#pragma unroll
    for (int k = 0; k < 4; ++k) {
        float lo = s0 ? v[2 * k + 1] : v[2 * k];
        float hi = s0 ? v[2 * k] : v[2 * k + 1];
        w[k] = lo + __shfl_xor(hi, 1, 64);
    }
    const bool s1 = (lane & 2) != 0;
#pragma unroll
    for (int k = 0; k < 2; ++k) {
        float lo = s1 ? w[2 * k + 1] : w[2 * k];
        float hi = s1 ? w[2 * k] : w[2 * k + 1];
        w[k] = lo + __shfl_xor(hi, 2, 64);
    }
    const bool s2 = (lane & 4) != 0;
    float lo = s2 ? w[1] : w[0];
    float hi = s2 ? w[0] : w[1];
    float r = lo + __shfl_xor(hi, 4, 64);
    r += __shfl_xor(r, 8, 64);
    r += __shfl_xor(r, 16, 64);
    r += __shfl_xor(r, 32, 64);
    return r;
}

// ---------------- Layer 1: input channel [B,4,U,A] ----------------
// 256 thr = 128 antennas x 2 channel-groups. Group cg computes output
// channels [cg*16, cg*16+16).
template <int NZ>
__global__ __launch_bounds__(256) void layer_first_t(
    const float* __restrict__ ch, const float* __restrict__ W1,
    const float* __restrict__ b1, unsigned short* __restrict__ ll_out,
    float* __restrict__ lg_out, float* __restrict__ gl_out,
    float* __restrict__ gg_out)
{
    constexpr int UN = NU / NZ;
    const int b = blockIdx.x;
    const int al = threadIdx.x & 127;
    const int cg = threadIdx.x >> 7;       // wave-uniform (waves 0,1 / 2,3)
    const int a = blockIdx.y * 128 + al;
    const int uz = blockIdx.z;
    const int lane = threadIdx.x & 63;
    const v2f zero = v2f{0.f, 0.f};

    v2f acc0[4], acc1[4];                   // cg1: gl, gg accumulators
#pragma unroll
    for (int i = 0; i < 4; ++i) { acc0[i] = zero; acc1[i] = zero; }

    const v2f* bb = reinterpret_cast<const v2f*>(b1 + cg * 16);

#pragma unroll
    for (int k = 0; k < UN; ++k) {
        const int u = uz * UN + k;
        float x[4];
#pragma unroll
        for (int c = 0; c < 4; ++c)
            x[c] = ch[(((size_t)b * 4 + c) * NU + u) * NA + a];

        v2f y2[8];
#pragma unroll
        for (int o = 0; o < 8; ++o) y2[o] = bb[o];
#pragma unroll
        for (int jj = 0; jj < 2; ++jj)
#pragma unroll
            for (int c = 0; c < 4; ++c) {
                const v2f* wr = reinterpret_cast<const v2f*>(
                    W1 + ((cg * 2 + jj) * 4 + c) * 8);
                v2f xx = v2f{x[c], x[c]};
#pragma unroll
                for (int oi = 0; oi < 4; ++oi)
                    y2[jj * 4 + oi] = __builtin_elementwise_fma(xx, wr[oi], y2[jj * 4 + oi]);
            }
#pragma unroll
        for (int o = 0; o < 8; ++o) y2[o] = __builtin_elementwise_max(y2[o], zero);

        if (cg == 0) {
            const size_t xoff = (((size_t)(b * NU + u)) * NA + a) * 8;
            store8v(ll_out + xoff, y2);            // ch 0-7
            float ylg[8];                          // ch 8-15 -> lg
#pragma unroll
            for (int i = 0; i < 4; ++i) { ylg[2*i] = y2[4+i].x; ylg[2*i+1] = y2[4+i].y; }
            float lr = chan_reduce8(ylg, lane);
            if (lane < 8) atomicAdd(lg_out + (b * NU + u) * 8 + lane, lr);
        } else {
#pragma unroll
            for (int i = 0; i < 4; ++i) { acc0[i] += y2[i]; acc1[i] += y2[4+i]; }
        }
    }
    if (cg == 1) {
        const float invU = 1.f / 16.f;
        float4* gp = reinterpret_cast<float4*>(
            gl_out + (((size_t)uz * NB + b) * NA + a) * 8);
        gp[0] = make_float4(acc0[0].x*invU, acc0[0].y*invU, acc0[1].x*invU, acc0[1].y*invU);
        gp[1] = make_float4(acc0[2].x*invU, acc0[2].y*invU, acc0[3].x*invU, acc0[3].y*invU);
        float gga[8];
#pragma unroll
        for (int i = 0; i < 4; ++i) { gga[2*i] = acc1[i].x; gga[2*i+1] = acc1[i].y; }
        float gr = chan_reduce8(gga, lane);
        if (lane < 8) atomicAdd(gg_out + b * 8 + lane, gr);
    }
}

// -------- prep: base[b,u,32] = bias + lg·W_lg + gg·W_gg (optional input skip) ----
__global__ __launch_bounds__(256) void prep_base_k(
    const float* __restrict__ lg_sum, const float* __restrict__ lg_skip,
    const float* __restrict__ gg_sum, const float* __restrict__ gg_skip,
    const float* __restrict__ Wl, const float* __restrict__ bl,
    float* __restrict__ base)
{
    const int t = blockIdx.x * 256 + threadIdx.x;  // b*16+u
    if (t >= NB * NU) return;
    const int b = t >> 4;
    const float invA = 1.f / 1024.f, invUA = 1.f / 16384.f;
    float lg[8], gg[8];
#pragma unroll
    for (int c = 0; c < 8; ++c) {
        float v = lg_sum[t * 8 + c] * invA;
        if (lg_skip) v = (v + lg_skip[t * 8 + c] * invA) * 0.5f;
        lg[c] = v;
    }
#pragma unroll
    for (int c = 0; c < 8; ++c) {
        float v = gg_sum[b * 8 + c] * invUA;
        if (gg_skip) v = (v + gg_skip[b * 8 + c] * invUA) * 0.5f;
        gg[c] = v;
    }
    float y[32];
#pragma unroll
    for (int o = 0; o < 32; ++o) y[o] = bl[o];
#pragma unroll
    for (int j = 0; j < 4; ++j)
#pragma unroll
        for (int c = 0; c < 8; ++c) {
            const float* wl = Wl + (j * 32 + 8 + c) * 8;
            const float* wg = Wl + (j * 32 + 24 + c) * 8;
#pragma unroll
            for (int oi = 0; oi < 8; ++oi) {
                y[j * 8 + oi] = fmaf(lg[c], wl[oi], y[j * 8 + oi]);
                y[j * 8 + oi] = fmaf(gg[c], wg[oi], y[j * 8 + oi]);
            }
        }
#pragma unroll
    for (int o = 0; o < 32; ++o) base[t * 32 + o] = y[o];
}

// ---------------- Layers 2..7 main (channel-split) ----------------
// INPLACE=false: ll_in != ll_out (ping-pong), no intra-block race.
// INPLACE=true : ll_in == ll_out; per-u __syncthreads() (compiler drains
// vmcnt before s_barrier) guarantees all waves have LOADED u=k (prefetched
// at iter k-1) before group0 stores u=k.
template <int NZ, bool INPLACE>
__global__ __launch_bounds__(256) void layer_main_t(
    const unsigned short* ll_in, const float* __restrict__ gl_in,
    const float* __restrict__ gl_skip, const float* __restrict__ base,
    const float* __restrict__ Wl,
    const unsigned short* __restrict__ ll_skip,          // layer 7: f3 ll
    const float* __restrict__ ch, const float* __restrict__ W1,
    const float* __restrict__ b1,                        // layer 5: recompute f1 ll
    unsigned short* ll_out, float* __restrict__ lg_out,
    float* __restrict__ gl_out, float* __restrict__ gg_out)
{
    constexpr int UN = NU / NZ;
    const int b = blockIdx.x;
    const int al = threadIdx.x & 127;
    const int cg = threadIdx.x >> 7;       // wave-uniform
    const int a = blockIdx.y * 128 + al;
    const int uz = blockIdx.z;
    const int lane = threadIdx.x & 63;
    const v2f zero = v2f{0.f, 0.f};

    // gl gather (+ optional skip average)
    float g[8];
    {
        float si[8];
#pragma unroll
        for (int i = 0; i < 8; ++i) si[i] = 0.f;
#pragma unroll
        for (int z = 0; z < NZ; ++z) {
            const float4* gp = reinterpret_cast<const float4*>(
                gl_in + (((size_t)z * NB + b) * NA + a) * 8);
            float4 g0 = gp[0], g1 = gp[1];
            si[0] += g0.x; si[1] += g0.y; si[2] += g0.z; si[3] += g0.w;
            si[4] += g1.x; si[5] += g1.y; si[6] += g1.z; si[7] += g1.w;
        }
        if (gl_skip) {
            float ss[8];
#pragma unroll
            for (int i = 0; i < 8; ++i) ss[i] = 0.f;
#pragma unroll
            for (int z = 0; z < NZ; ++z) {
                const float4* sp = reinterpret_cast<const float4*>(
                    gl_skip + (((size_t)z * NB + b) * NA + a) * 8);
                float4 s0 = sp[0], s1 = sp[1];
                ss[0] += s0.x; ss[1] += s0.y; ss[2] += s0.z; ss[3] += s0.w;
                ss[4] += s1.x; ss[5] += s1.y; ss[6] += s1.z; ss[7] += s1.w;
            }
#pragma unroll
            for (int i = 0; i < 8; ++i) g[i] = (si[i] + ss[i]) * 0.5f;
        } else {
#pragma unroll
            for (int i = 0; i < 8; ++i) g[i] = si[i];
        }
    }
    // this group's 16-channel gl contribution (per-thread constant over u)
    v2f cgl2[8];
#pragma unroll
    for (int o = 0; o < 8; ++o) cgl2[o] = zero;
#pragma unroll
    for (int jj = 0; jj < 2; ++jj)
#pragma unroll
        for (int c = 0; c < 8; ++c) {
            const v2f* wr = reinterpret_cast<const v2f*>(
                Wl + ((cg * 2 + jj) * 32 + 16 + c) * 8);
            v2f xx = v2f{g[c], g[c]};
#pragma unroll
            for (int oi = 0; oi < 4; ++oi)
                cgl2[jj * 4 + oi] = __builtin_elementwise_fma(xx, wr[oi], cgl2[jj * 4 + oi]);
        }

    v2f acc0[4], acc1[4];                   // cg1: gl, gg accumulators
#pragma unroll
    for (int i = 0; i < 4; ++i) { acc0[i] = zero; acc1[i] = zero; }

    const unsigned short* llp =
        ll_in + (((size_t)(b * NU + uz * UN)) * NA + a) * 8;
    const size_t ustride = (size_t)NA * 8;
    uint4 xv = *reinterpret_cast<const uint4*>(llp);

#pragma unroll
    for (int k = 0; k < UN; ++k) {
        const int u = uz * UN + k;
        uint4 xnext = xv;
        if (k + 1 < UN)
            xnext = *reinterpret_cast<const uint4*>(llp + (size_t)(k + 1) * ustride);
        if (INPLACE) __syncthreads();   // all waves' loads of u=k done

        const v2f* bp2 = reinterpret_cast<const v2f*>(
            base + (b * NU + u) * 32 + cg * 16);      // wave-uniform -> s_load
        v2f y2[8];
#pragma unroll
        for (int o = 0; o < 8; ++o) y2[o] = cgl2[o] + bp2[o];

        float x[8];
        unpack8(xv, x);
#pragma unroll
        for (int jj = 0; jj < 2; ++jj)
#pragma unroll
            for (int c = 0; c < 8; ++c) {
                const v2f* wr = reinterpret_cast<const v2f*>(
                    Wl + ((cg * 2 + jj) * 32 + c) * 8);
                v2f xx = v2f{x[c], x[c]};
#pragma unroll
                for (int oi = 0; oi < 4; ++oi)
                    y2[jj * 4 + oi] = __builtin_elementwise_fma(xx, wr[oi], y2[jj * 4 + oi]);
            }
#pragma unroll
        for (int o = 0; o < 8; ++o) y2[o] = __builtin_elementwise_max(y2[o], zero);

        if (cg == 0) {
            const size_t xoff = (((size_t)(b * NU + u)) * NA + a) * 8;
            v2f out2[4];
#pragma unroll
            for (int i = 0; i < 4; ++i) out2[i] = y2[i];
            if (ll_skip) {                   // layer 7: average with stored f3 ll
                v2f s2[4];
                unpack8v(*reinterpret_cast<const uint4*>(ll_skip + xoff), s2);
#pragma unroll
                for (int i = 0; i < 4; ++i) out2[i] = (out2[i] + s2[i]) * 0.5f;
            } else if (ch) {                 // layer 5: recompute f1 ll from input
                float xc[4];
#pragma unroll
                for (int c = 0; c < 4; ++c)
                    xc[c] = ch[(((size_t)b * 4 + c) * NU + u) * NA + a];
                v2f s2[4];
                const v2f* b12 = reinterpret_cast<const v2f*>(b1);
#pragma unroll
                for (int i = 0; i < 4; ++i) s2[i] = b12[i];
#pragma unroll
                for (int c = 0; c < 4; ++c) {
                    const v2f* w2 = reinterpret_cast<const v2f*>(W1 + c * 8);
                    v2f xx = v2f{xc[c], xc[c]};
#pragma unroll
                    for (int i = 0; i < 4; ++i)
                        s2[i] = __builtin_elementwise_fma(xx, w2[i], s2[i]);
                }
#pragma unroll
                for (int i = 0; i < 4; ++i)
                    out2[i] = (out2[i] + __builtin_elementwise_max(s2[i], zero)) * 0.5f;
            }
            store8v(ll_out + xoff, out2);

            float ylg[8];                    // ch 8-15 -> lg
#pragma unroll
            for (int i = 0; i < 4; ++i) { ylg[2*i] = y2[4+i].x; ylg[2*i+1] = y2[4+i].y; }
            float lr = chan_reduce8(ylg, lane);
            if (lane < 8) atomicAdd(lg_out + (b * NU + u) * 8 + lane, lr);
        } else {
#pragma unroll
            for (int i = 0; i < 4; ++i) { acc0[i] += y2[i]; acc1[i] += y2[4+i]; }
        }
        xv = xnext;
    }
    if (cg == 1) {
        const float invU = 1.f / 16.f;
        float4* gp = reinterpret_cast<float4*>(
            gl_out + (((size_t)uz * NB + b) * NA + a) * 8);
        gp[0] = make_float4(acc0[0].x*invU, acc0[0].y*invU, acc0[1].x*invU, acc0[1].y*invU);
        gp[1] = make_float4(acc0[2].x*invU, acc0[2].y*invU, acc0[3].x*invU, acc0[3].y*invU);
        float gga[8];
#pragma unroll
        for (int i = 0; i < 4; ++i) { gga[2*i] = acc1[i].x; gga[2*i+1] = acc1[i].y; }
        float gr = chan_reduce8(gga, lane);
        if (lane < 8) atomicAdd(gg_out + b * 8 + lane, gr);
    }
}

// ---------------- Layer 8: out[b,a] = pi * (mean_u f·W8 + b8) ----------------
template <int NZ>
__global__ __launch_bounds__(256) void layer_out_t(
    const unsigned short* __restrict__ ll,   // f7' ll (skip already applied)
    const float* __restrict__ lg7, const float* __restrict__ lg3,  // raw sums
    const float* __restrict__ gl7, const float* __restrict__ gl3,  // partial means
    const float* __restrict__ gg7, const float* __restrict__ gg3,  // raw sums
    const float* __restrict__ W8, const float* __restrict__ b8,
    float* __restrict__ out)
{
    constexpr int UN = NU / NZ;
    const int b = blockIdx.x;
    const int a = blockIdx.y * 256 + threadIdx.x;
    const int uz = blockIdx.z;
    const float invA = 1.f / 1024.f, invUA = 1.f / 16384.f, invU = 1.f / 16.f;

    float acc = 0.f;
#pragma unroll
    for (int k = 0; k < UN; ++k) {
        const int u = uz * UN + k;
        float x[8];
        uint4 v = *reinterpret_cast<const uint4*>(
            ll + (((size_t)(b * NU + u)) * NA + a) * 8);
        unpack8(v, x);
#pragma unroll
        for (int c = 0; c < 8; ++c) acc += x[c] * W8[c];
    }
    acc *= invU;

    if (uz == 0) {
        float sb = b8[0];
#pragma unroll
        for (int c = 0; c < 8; ++c) {
            float s7 = 0.f, s3 = 0.f;
#pragma unroll
            for (int u = 0; u < NU; ++u) {
                s7 += lg7[(b * NU + u) * 8 + c];
                s3 += lg3[(b * NU + u) * 8 + c];
            }
            sb += ((s7 * invA + s3 * invA) * 0.5f * invU) * W8[8 + c];
        }
#pragma unroll
        for (int c = 0; c < 8; ++c)
            sb += ((gg7[b * 8 + c] + gg3[b * 8 + c]) * invUA * 0.5f) * W8[24 + c];

        float s7[8], s3[8];
#pragma unroll
        for (int i = 0; i < 8; ++i) { s7[i] = 0.f; s3[i] = 0.f; }
#pragma unroll
        for (int z = 0; z < NZ; ++z) {
            const float4* g7 = reinterpret_cast<const float4*>(
                gl7 + (((size_t)z * NB + b) * NA + a) * 8);
            const float4* g3 = reinterpret_cast<const float4*>(
                gl3 + (((size_t)z * NB + b) * NA + a) * 8);
            float4 a0 = g7[0], a1 = g7[1], b0 = g3[0], b1v = g3[1];
            s7[0] += a0.x; s7[1] += a0.y; s7[2] += a0.z; s7[3] += a0.w;
            s7[4] += a1.x; s7[5] += a1.y; s7[6] += a1.z; s7[7] += a1.w;
            s3[0] += b0.x; s3[1] += b0.y; s3[2] += b0.z; s3[3] += b0.w;
            s3[4] += b1v.x; s3[5] += b1v.y; s3[6] += b1v.z; s3[7] += b1v.w;
        }
#pragma unroll
        for (int i = 0; i < 8; ++i)
            acc += 0.5f * (s7[i] + s3[i]) * W8[16 + i];
        acc += sb;
    }
    atomicAdd(out + (size_t)b * NA + a, acc * PI_F);
}

// ---------------- host ----------------
static constexpr size_t LLsz = (size_t)NB * NU * NA * 8;  // elems
static constexpr size_t GLsz = (size_t)NB * NA * 8;
static constexpr size_t LGsz = (size_t)NB * NU * 8;
static constexpr size_t GGsz = (size_t)NB * 8;

// Primary: 3 ll buffers (A, B, f3s), non-in-place everywhere.
template <int NZ>
static void run_pipeline3(const float* channel, const float* W1, const float* b1,
                          const float* Wm, const float* bm, const float* W8,
                          const float* b8, float* out, int out_bytes,
                          void* d_ws, hipStream_t stream)
{
    unsigned short* A  = (unsigned short*)d_ws;
    unsigned short* Bf = A + LLsz;
    unsigned short* f3s = Bf + LLsz;
    float* glb = (float*)(f3s + LLsz);                  // 4 bufs x NZ*GL fp32
    float* g0 = glb;
    float* g1 = glb + (size_t)NZ * GLsz;
    float* g2 = glb + (size_t)2 * NZ * GLsz;
    float* g3 = glb + (size_t)3 * NZ * GLsz;
    float* lgb = glb + (size_t)4 * NZ * GLsz;           // 7 x LG
    float* ggb = lgb + 7 * LGsz;                        // 7 x GG
    float* base = ggb + 7 * GGsz;                       // 2048 x 32

    hipMemsetAsync(lgb, 0, (7 * LGsz + 7 * GGsz) * sizeof(float), stream);
    hipMemsetAsync(out, 0, out_bytes, stream);

    dim3 grid(NB, NA / 128, NZ), blk(256);
    dim3 ogrid(NB, NA / 256, NZ);

    // L1 -> A
    layer_first_t<NZ><<<grid, blk, 0, stream>>>(channel, W1, b1, A, lgb, g0, ggb);
    // L2: A -> B, g0 -> g2
    prep_base_k<<<8, 256, 0, stream>>>(lgb, nullptr, ggb, nullptr, Wm, bm, base);
    layer_main_t<NZ, false><<<grid, blk, 0, stream>>>(A, g0, nullptr, base, Wm,
        nullptr, nullptr, nullptr, nullptr, Bf, lgb + 1 * LGsz, g2, ggb + 1 * GGsz);
    // L3: B -> f3s (pinned), g2 -> g1
    prep_base_k<<<8, 256, 0, stream>>>(lgb + 1 * LGsz, nullptr, ggb + 1 * GGsz, nullptr,
                                       Wm + 1024, bm + 32, base);
    layer_main_t<NZ, false><<<grid, blk, 0, stream>>>(Bf, g2, nullptr, base, Wm + 1024,
        nullptr, nullptr, nullptr, nullptr, f3s, lgb + 2 * LGsz, g1, ggb + 2 * GGsz);
    // L4: f3s -> A, g1 -> g3
    prep_base_k<<<8, 256, 0, stream>>>(lgb + 2 * LGsz, nullptr, ggb + 2 * GGsz, nullptr,
                                       Wm + 2048, bm + 64, base);
    layer_main_t<NZ, false><<<grid, blk, 0, stream>>>(f3s, g1, nullptr, base, Wm + 2048,
        nullptr, nullptr, nullptr, nullptr, A, lgb + 3 * LGsz, g3, ggb + 3 * GGsz);
    // L5: A -> B, g3 -> g2; ll-skip = recomputed f1 from channel
    prep_base_k<<<8, 256, 0, stream>>>(lgb + 3 * LGsz, nullptr, ggb + 3 * GGsz, nullptr,
                                       Wm + 3072, bm + 96, base);
    layer_main_t<NZ, false><<<grid, blk, 0, stream>>>(A, g3, nullptr, base, Wm + 3072,
        nullptr, channel, W1, b1, Bf, lgb + 4 * LGsz, g2, ggb + 4 * GGsz);
    // L6: B -> A, g2 -> g3; input-side skip with f1 factors
    prep_base_k<<<8, 256, 0, stream>>>(lgb + 4 * LGsz, lgb, ggb + 4 * GGsz, ggb,
                                       Wm + 4096, bm + 128, base);
    layer_main_t<NZ, false><<<grid, blk, 0, stream>>>(Bf, g2, g0, base, Wm + 4096,
        nullptr, nullptr, nullptr, nullptr, A, lgb + 5 * LGsz, g3, ggb + 5 * GGsz);
    // L7: A -> B, g3 -> g2; ll-skip = f3s
    prep_base_k<<<8, 256, 0, stream>>>(lgb + 5 * LGsz, nullptr, ggb + 5 * GGsz, nullptr,
                                       Wm + 5120, bm + 160, base);
    layer_main_t<NZ, false><<<grid, blk, 0, stream>>>(A, g3, nullptr, base, Wm + 5120,
        f3s, nullptr, nullptr, nullptr, Bf, lgb + 6 * LGsz, g2, ggb + 6 * GGsz);
    // L8
    layer_out_t<NZ><<<ogrid, blk, 0, stream>>>(Bf, lgb + 6 * LGsz, lgb + 2 * LGsz,
                                               g2, g1, ggb + 6 * GGsz, ggb + 2 * GGsz,
                                               W8, b8, out);
}

// Fallback: 2 ll buffers, in-place layers use per-u barrier sync.
template <int NZ>
static void run_pipeline2(const float* channel, const float* W1, const float* b1,
                          const float* Wm, const float* bm, const float* W8,
                          const float* b8, float* out, int out_bytes,
                          void* d_ws, hipStream_t stream)
{
    unsigned short* A = (unsigned short*)d_ws;
    unsigned short* f3s = A + LLsz;
    float* glb = (float*)(f3s + LLsz);
    float* g0 = glb;
    float* g1 = glb + (size_t)NZ * GLsz;
    float* g2 = glb + (size_t)2 * NZ * GLsz;
    float* g3 = glb + (size_t)3 * NZ * GLsz;
    float* lgb = glb + (size_t)4 * NZ * GLsz;
    float* ggb = lgb + 7 * LGsz;
    float* base = ggb + 7 * GGsz;

    hipMemsetAsync(lgb, 0, (7 * LGsz + 7 * GGsz) * sizeof(float), stream);
    hipMemsetAsync(out, 0, out_bytes, stream);

    dim3 grid(NB, NA / 128, NZ), blk(256);
    dim3 ogrid(NB, NA / 256, NZ);

    layer_first_t<NZ><<<grid, blk, 0, stream>>>(channel, W1, b1, A, lgb, g0, ggb);
    prep_base_k<<<8, 256, 0, stream>>>(lgb, nullptr, ggb, nullptr, Wm, bm, base);
    layer_main_t<NZ, true><<<grid, blk, 0, stream>>>(A, g0, nullptr, base, Wm,
        nullptr, nullptr, nullptr, nullptr, A, lgb + 1 * LGsz, g2, ggb + 1 * GGsz);
    prep_base_k<<<8, 256, 0, stream>>>(lgb + 1 * LGsz, nullptr, ggb + 1 * GGsz, nullptr,
                                       Wm + 1024, bm + 32, base);
    layer_main_t<NZ, false><<<grid, blk, 0, stream>>>(A, g2, nullptr, base, Wm + 1024,
        nullptr, nullptr, nullptr, nullptr, f3s, lgb + 2 * LGsz, g1, ggb + 2 * GGsz);
    prep_base_k<<<8, 256, 0, stream>>>(lgb + 2 * LGsz, nullptr, ggb + 2 * GGsz, nullptr,
                                       Wm + 2048, bm + 64, base);
    layer_main_t<NZ, false><<<grid, blk, 0, stream>>>(f3s, g1, nullptr, base, Wm + 2048,
        nullptr, nullptr, nullptr, nullptr, A, lgb + 3 * LGsz, g3, ggb + 3 * GGsz);
    prep_base_k<<<8, 256, 0, stream>>>(lgb + 3 * LGsz, nullptr, ggb + 3 * GGsz, nullptr,
                                       Wm + 3072, bm + 96, base);
    layer_main_t<NZ, true><<<grid, blk, 0, stream>>>(A, g3, nullptr, base, Wm + 3072,
        nullptr, channel, W1, b1, A, lgb + 4 * LGsz, g2, ggb + 4 * GGsz);
    prep_base_k<<<8, 256, 0, stream>>>(lgb + 4 * LGsz, lgb, ggb + 4 * GGsz, ggb,
                                       Wm + 4096, bm + 128, base);
    layer_main_t<NZ, true><<<grid, blk, 0, stream>>>(A, g2, g0, base, Wm + 4096,
        nullptr, nullptr, nullptr, nullptr, A, lgb + 5 * LGsz, g3, ggb + 5 * GGsz);
    prep_base_k<<<8, 256, 0, stream>>>(lgb + 5 * LGsz, nullptr, ggb + 5 * GGsz, nullptr,
                                       Wm + 5120, bm + 160, base);
    layer_main_t<NZ, true><<<grid, blk, 0, stream>>>(A, g3, nullptr, base, Wm + 5120,
        f3s, nullptr, nullptr, nullptr, A, lgb + 6 * LGsz, g2, ggb + 6 * GGsz);
    layer_out_t<NZ><<<ogrid, blk, 0, stream>>>(A, lgb + 6 * LGsz, lgb + 2 * LGsz,
                                               g2, g1, ggb + 6 * GGsz, ggb + 2 * GGsz,
                                               W8, b8, out);
}

static size_t misc_bytes() {
    return (7 * LGsz + 7 * GGsz + 2048 * 32) * sizeof(float);
}
static size_t ws_req3(int nz) {
    return LLsz * 3 * sizeof(unsigned short)
         + (size_t)4 * nz * GLsz * sizeof(float) + misc_bytes();
}
static size_t ws_req2(int nz) {
    return LLsz * 2 * sizeof(unsigned short)
         + (size_t)4 * nz * GLsz * sizeof(float) + misc_bytes();
}

extern "C" void kernel_launch(void* const* d_in, const int* in_sizes, int n_in,
                              void* d_out, int out_size, void* d_ws, size_t ws_size,
                              hipStream_t stream) {
    const float* channel = (const float*)d_in[0];
    const float* W1 = (const float*)d_in[1];
    const float* b1 = (const float*)d_in[2];
    const float* Wm = (const float*)d_in[3];
    const float* bm = (const float*)d_in[4];
    const float* W8 = (const float*)d_in[5];
    const float* b8 = (const float*)d_in[6];
    float* out = (float*)d_out;

    if (ws_size >= ws_req3(2)) {
        run_pipeline3<2>(channel, W1, b1, Wm, bm, W8, b8, out, out_size, d_ws, stream);
    } else if (ws_size >= ws_req2(2)) {
        run_pipeline2<2>(channel, W1, b1, Wm, bm, W8, b8, out, out_size, d_ws, stream);
    } else {
        run_pipeline2<1>(channel, W1, b1, Wm, bm, W8, b8, out, out_size, d_ws, stream);
    }
}

// Round 7
// 432.045 us; speedup vs baseline: 1.6578x; 1.6578x over previous
//
#include <hip/hip_runtime.h>

// RISnetPIv2: B=128, U=16, A=1024, FEAT=4, INFO=8.
// e_u/e_a uniform averaging -> 32-ch feature factors into ll[B,U,A,8] (bf16),
// lg[B,U,8], gl[B,A,8], gg[B,8] (fp32).
// Round-7: round-6 minus the illegal instruction. gfx950 has NO v_pk_max_f32
// (fp32 VOP3P = fma/add/mul only; packed max is fp16-only) -> relu via two
// scalar v_max_f32. v_pk_fma_f32 / v_pk_add_f32 assembled fine in r6 and
// carry the main win: conv 256->128 FMA issue slots, cgl 128->64.
// Base = r2 skeleton (best: 61.3us/layer, 52 VGPR, NZ=4, 128thr, in-place),
// + v_cvt_pk_bf16_f32 stores + merge3+LDS ds_add lg reduce (r3/r4-proven),
// + NO occupancy pin (r1/r3 lesson: pinning forces VGPR down -> spills).

#define NB 128
#define NU 16
#define NA 1024

typedef float v2f __attribute__((ext_vector_type(2)));

static constexpr float PI_F = 3.14159265358979323846f;

// ---- forced VOP3P packed fp32 (bit-identical IEEE fp32 per half) ----
__device__ __forceinline__ v2f pk_fma(v2f a, v2f b, v2f c) {
    v2f d;
    asm("v_pk_fma_f32 %0, %1, %2, %3" : "=v"(d) : "v"(a), "v"(b), "v"(c));
    return d;
}
__device__ __forceinline__ v2f pk_add(v2f a, v2f b) {
    v2f d;
    asm("v_pk_add_f32 %0, %1, %2" : "=v"(d) : "v"(a), "v"(b));
    return d;
}
// no v_pk_max_f32 on gfx950 -> scalar halves (v_max_f32 x2)
__device__ __forceinline__ v2f relu2(v2f a) {
    return v2f{__builtin_fmaxf(a.x, 0.f), __builtin_fmaxf(a.y, 0.f)};
}

__device__ __forceinline__ void unpack8(uint4 v, float x[8]) {
    x[0] = __uint_as_float(v.x << 16); x[1] = __uint_as_float(v.x & 0xffff0000u);
    x[2] = __uint_as_float(v.y << 16); x[3] = __uint_as_float(v.y & 0xffff0000u);
    x[4] = __uint_as_float(v.z << 16); x[5] = __uint_as_float(v.z & 0xffff0000u);
    x[6] = __uint_as_float(v.w << 16); x[7] = __uint_as_float(v.w & 0xffff0000u);
}
__device__ __forceinline__ void unpack8v(uint4 v, v2f x2[4]) {
    x2[0] = v2f{__uint_as_float(v.x << 16), __uint_as_float(v.x & 0xffff0000u)};
    x2[1] = v2f{__uint_as_float(v.y << 16), __uint_as_float(v.y & 0xffff0000u)};
    x2[2] = v2f{__uint_as_float(v.z << 16), __uint_as_float(v.z & 0xffff0000u)};
    x2[3] = v2f{__uint_as_float(v.w << 16), __uint_as_float(v.w & 0xffff0000u)};
}
__device__ __forceinline__ unsigned int cvtpk(float a, float b) {
    unsigned int r;
    asm("v_cvt_pk_bf16_f32 %0, %1, %2" : "=v"(r) : "v"(a), "v"(b));
    return r;  // lo = bf16(a), hi = bf16(b), RNE
}
__device__ __forceinline__ void store8v(unsigned short* p, const v2f y2[4]) {
    uint4 v;
    v.x = cvtpk(y2[0].x, y2[0].y); v.y = cvtpk(y2[1].x, y2[1].y);
    v.z = cvtpk(y2[2].x, y2[2].y); v.w = cvtpk(y2[3].x, y2[3].y);
    *reinterpret_cast<uint4*>(p) = v;
}

// 3-level channel-merging butterfly: input v2 pairs y[0..3] (8 channels);
// output: lane l holds sum of channel (l&7) over its 8-lane group.
// Follow with LDS atomic add from all 64 lanes for full block sum.
__device__ __forceinline__ float merge3v(const v2f* y, int lane) {
    float w[4];
    const bool s0 = (lane & 1) != 0;
#pragma unroll
    for (int k = 0; k < 4; ++k) {
        float lo = s0 ? y[k].y : y[k].x;
        float hi = s0 ? y[k].x : y[k].y;
        w[k] = lo + __shfl_xor(hi, 1, 64);
    }
    const bool s1 = (lane & 2) != 0;
#pragma unroll
    for (int k = 0; k < 2; ++k) {
        float lo = s1 ? w[2 * k + 1] : w[2 * k];
        float hi = s1 ? w[2 * k] : w[2 * k + 1];
        w[k] = lo + __shfl_xor(hi, 2, 64);
    }
    const bool s2 = (lane & 4) != 0;
    float lo = s2 ? w[1] : w[0];
    float hi = s2 ? w[0] : w[1];
    return lo + __shfl_xor(hi, 4, 64);
}

// ---------------- Layer 1: input channel [B,4,U,A] ----------------
template <int NZ>
__global__ __launch_bounds__(128) void layer_first_t(
    const float* __restrict__ ch, const float* __restrict__ W1,
    const float* __restrict__ b1, unsigned short* __restrict__ ll_out,
    float* __restrict__ lg_out, float* __restrict__ gl_out,
    float* __restrict__ gg_out)
{
    constexpr int UN = NU / NZ;
    const int b = blockIdx.x;
    const int a = blockIdx.y * 128 + threadIdx.x;
    const int uz = blockIdx.z;
    const int lane = threadIdx.x & 63;
    const int tid = threadIdx.x;
    const v2f zero = v2f{0.f, 0.f};

    __shared__ float s_lg[UN][8];
    __shared__ float s_gg[8];
    if (tid < UN * 8) s_lg[tid >> 3][tid & 7] = 0.f;
    if (tid >= 64 && tid < 72) s_gg[tid & 7] = 0.f;
    __syncthreads();

    v2f glacc2[4], ggacc2[4];
#pragma unroll
    for (int i = 0; i < 4; ++i) { glacc2[i] = zero; ggacc2[i] = zero; }

#pragma unroll
    for (int k = 0; k < UN; ++k) {
        const int u = uz * UN + k;
        float x[4];
#pragma unroll
        for (int c = 0; c < 4; ++c)
            x[c] = ch[(((size_t)b * 4 + c) * NU + u) * NA + a];

        v2f y2[16];
        const v2f* b2 = reinterpret_cast<const v2f*>(b1);
#pragma unroll
        for (int o = 0; o < 16; ++o) y2[o] = b2[o];
#pragma unroll
        for (int c = 0; c < 4; ++c) {
            const v2f xx = v2f{x[c], x[c]};
#pragma unroll
            for (int j = 0; j < 4; ++j) {
                const v2f* wr = reinterpret_cast<const v2f*>(W1 + (j * 4 + c) * 8);
#pragma unroll
                for (int oi = 0; oi < 4; ++oi)
                    y2[j * 4 + oi] = pk_fma(xx, wr[oi], y2[j * 4 + oi]);
            }
        }
#pragma unroll
        for (int o = 0; o < 16; ++o) y2[o] = relu2(y2[o]);

        const size_t xoff = (((size_t)(b * NU + u)) * NA + a) * 8;
        store8v(ll_out + xoff, y2);                     // ch 0-7

#pragma unroll
        for (int i = 0; i < 4; ++i) glacc2[i] = pk_add(glacc2[i], y2[8 + i]);
#pragma unroll
        for (int i = 0; i < 4; ++i) ggacc2[i] = pk_add(ggacc2[i], y2[12 + i]);

        float lr = merge3v(y2 + 4, lane);               // ch 8-15 -> lg
        atomicAdd(&s_lg[k][lane & 7], lr);
    }
    {   // gl partial for this u-slice (scaled 1/U; partials sum to mean)
        const float invU = 1.f / 16.f;
        float4* gp = reinterpret_cast<float4*>(
            gl_out + (((size_t)uz * NB + b) * NA + a) * 8);
        gp[0] = make_float4(glacc2[0].x*invU, glacc2[0].y*invU, glacc2[1].x*invU, glacc2[1].y*invU);
        gp[1] = make_float4(glacc2[2].x*invU, glacc2[2].y*invU, glacc2[3].x*invU, glacc2[3].y*invU);
    }
    float gr = merge3v(ggacc2, lane);
    atomicAdd(&s_gg[lane & 7], gr);
    __syncthreads();
    if (tid < UN * 8)
        atomicAdd(lg_out + ((size_t)b * NU + uz * UN + (tid >> 3)) * 8 + (tid & 7),
                  s_lg[tid >> 3][tid & 7]);
    if (tid >= 64 && tid < 72)
        atomicAdd(gg_out + b * 8 + (tid & 7), s_gg[tid & 7]);
}

// -------- prep: base[b,u,32] = bias + lg·W_lg + gg·W_gg (optional input skip) ----
__global__ __launch_bounds__(256) void prep_base_k(
    const float* __restrict__ lg_sum, const float* __restrict__ lg_skip,
    const float* __restrict__ gg_sum, const float* __restrict__ gg_skip,
    const float* __restrict__ Wl, const float* __restrict__ bl,
    float* __restrict__ base)
{
    const int t = blockIdx.x * 256 + threadIdx.x;  // b*16+u
    if (t >= NB * NU) return;
    const int b = t >> 4;
    const float invA = 1.f / 1024.f, invUA = 1.f / 16384.f;
    float lg[8], gg[8];
#pragma unroll
    for (int c = 0; c < 8; ++c) {
        float v = lg_sum[t * 8 + c] * invA;
        if (lg_skip) v = (v + lg_skip[t * 8 + c] * invA) * 0.5f;
        lg[c] = v;
    }
#pragma unroll
    for (int c = 0; c < 8; ++c) {
        float v = gg_sum[b * 8 + c] * invUA;
        if (gg_skip) v = (v + gg_skip[b * 8 + c] * invUA) * 0.5f;
        gg[c] = v;
    }
    float y[32];
#pragma unroll
    for (int o = 0; o < 32; ++o) y[o] = bl[o];
#pragma unroll
    for (int j = 0; j < 4; ++j)
#pragma unroll
        for (int c = 0; c < 8; ++c) {
            const float* wl = Wl + (j * 32 + 8 + c) * 8;
            const float* wg = Wl + (j * 32 + 24 + c) * 8;
#pragma unroll
            for (int oi = 0; oi < 8; ++oi) {
                y[j * 8 + oi] = fmaf(lg[c], wl[oi], y[j * 8 + oi]);
                y[j * 8 + oi] = fmaf(gg[c], wg[oi], y[j * 8 + oi]);
            }
        }
#pragma unroll
    for (int o = 0; o < 32; ++o) base[t * 32 + o] = y[o];
}

// ---------------- Layers 2..7 main ----------------
// ll_in / ll_out may alias (per-thread read-then-write of same position;
// prefetch of u+1 is this thread's own position, written only at its own
// k+1 iteration -> safe; z-blocks own disjoint u-slices).
template <int NZ>
__global__ __launch_bounds__(128) void layer_main_t(
    const unsigned short* ll_in, const float* __restrict__ gl_in,
    const float* __restrict__ gl_skip, const float* __restrict__ base,
    const float* __restrict__ Wl,
    const unsigned short* __restrict__ ll_skip,          // layer 7: f3 ll
    const float* __restrict__ ch, const float* __restrict__ W1,
    const float* __restrict__ b1,                        // layer 5: recompute f1 ll
    unsigned short* ll_out, float* __restrict__ lg_out,
    float* __restrict__ gl_out, float* __restrict__ gg_out)
{
    constexpr int UN = NU / NZ;
    const int b = blockIdx.x;
    const int a = blockIdx.y * 128 + threadIdx.x;
    const int uz = blockIdx.z;
    const int lane = threadIdx.x & 63;
    const int tid = threadIdx.x;
    const v2f zero = v2f{0.f, 0.f};

    __shared__ float s_lg[UN][8];
    __shared__ float s_gg[8];
    if (tid < UN * 8) s_lg[tid >> 3][tid & 7] = 0.f;
    if (tid >= 64 && tid < 72) s_gg[tid & 7] = 0.f;
    __syncthreads();

    // gl gather (+ optional skip average)
    float g[8];
    {
        float si[8];
#pragma unroll
        for (int i = 0; i < 8; ++i) si[i] = 0.f;
#pragma unroll
        for (int z = 0; z < NZ; ++z) {
            const float4* gp = reinterpret_cast<const float4*>(
                gl_in + (((size_t)z * NB + b) * NA + a) * 8);
            float4 g0 = gp[0], g1 = gp[1];
            si[0] += g0.x; si[1] += g0.y; si[2] += g0.z; si[3] += g0.w;
            si[4] += g1.x; si[5] += g1.y; si[6] += g1.z; si[7] += g1.w;
        }
        if (gl_skip) {
            float ss[8];
#pragma unroll
            for (int i = 0; i < 8; ++i) ss[i] = 0.f;
#pragma unroll
            for (int z = 0; z < NZ; ++z) {
                const float4* sp = reinterpret_cast<const float4*>(
                    gl_skip + (((size_t)z * NB + b) * NA + a) * 8);
                float4 s0 = sp[0], s1 = sp[1];
                ss[0] += s0.x; ss[1] += s0.y; ss[2] += s0.z; ss[3] += s0.w;
                ss[4] += s1.x; ss[5] += s1.y; ss[6] += s1.z; ss[7] += s1.w;
            }
#pragma unroll
            for (int i = 0; i < 8; ++i) g[i] = (si[i] + ss[i]) * 0.5f;
        } else {
#pragma unroll
            for (int i = 0; i < 8; ++i) g[i] = si[i];
        }
    }
    // cgl = gl contribution to all 32 out-channels (constant over u)
    v2f cgl2[16];
#pragma unroll
    for (int o = 0; o < 16; ++o) cgl2[o] = zero;
#pragma unroll
    for (int c = 0; c < 8; ++c) {
        const v2f xx = v2f{g[c], g[c]};
#pragma unroll
        for (int j = 0; j < 4; ++j) {
            const v2f* wr = reinterpret_cast<const v2f*>(Wl + (j * 32 + 16 + c) * 8);
#pragma unroll
            for (int oi = 0; oi < 4; ++oi)
                cgl2[j * 4 + oi] = pk_fma(xx, wr[oi], cgl2[j * 4 + oi]);
        }
    }

    v2f glacc2[4], ggacc2[4];
#pragma unroll
    for (int i = 0; i < 4; ++i) { glacc2[i] = zero; ggacc2[i] = zero; }

    const unsigned short* llp =
        ll_in + (((size_t)(b * NU + uz * UN)) * NA + a) * 8;
    const size_t ustride = (size_t)NA * 8;
    uint4 xv = *reinterpret_cast<const uint4*>(llp);

#pragma unroll
    for (int k = 0; k < UN; ++k) {
        const int u = uz * UN + k;
        uint4 xnext = xv;
        if (k + 1 < UN)
            xnext = *reinterpret_cast<const uint4*>(llp + (size_t)(k + 1) * ustride);

        const v2f* bp2 = reinterpret_cast<const v2f*>(base + (b * NU + u) * 32);
        v2f y2[16];
#pragma unroll
        for (int o = 0; o < 16; ++o) y2[o] = pk_add(cgl2[o], bp2[o]);

        float x[8];
        unpack8(xv, x);
#pragma unroll
        for (int c = 0; c < 8; ++c) {
            const v2f xx = v2f{x[c], x[c]};
#pragma unroll
            for (int j = 0; j < 4; ++j) {
                const v2f* wr = reinterpret_cast<const v2f*>(Wl + (j * 32 + c) * 8);
#pragma unroll
                for (int oi = 0; oi < 4; ++oi)
                    y2[j * 4 + oi] = pk_fma(xx, wr[oi], y2[j * 4 + oi]);
            }
        }
#pragma unroll
        for (int o = 0; o < 16; ++o) y2[o] = relu2(y2[o]);

        const size_t xoff = (((size_t)(b * NU + u)) * NA + a) * 8;
        v2f out2[4];
#pragma unroll
        for (int i = 0; i < 4; ++i) out2[i] = y2[i];
        if (ll_skip) {                       // layer 7: average with stored f3 ll
            v2f s2[4];
            unpack8v(*reinterpret_cast<const uint4*>(ll_skip + xoff), s2);
#pragma unroll
            for (int i = 0; i < 4; ++i) out2[i] = (out2[i] + s2[i]) * 0.5f;
        } else if (ch) {                     // layer 5: recompute f1 ll from input
            float xc[4];
#pragma unroll
            for (int c = 0; c < 4; ++c)
                xc[c] = ch[(((size_t)b * 4 + c) * NU + u) * NA + a];
            v2f s2[4];
            const v2f* b12 = reinterpret_cast<const v2f*>(b1);
#pragma unroll
            for (int i = 0; i < 4; ++i) s2[i] = b12[i];
#pragma unroll
            for (int c = 0; c < 4; ++c) {
                const v2f* w2 = reinterpret_cast<const v2f*>(W1 + c * 8);
                const v2f xx = v2f{xc[c], xc[c]};
#pragma unroll
                for (int i = 0; i < 4; ++i) s2[i] = pk_fma(xx, w2[i], s2[i]);
            }
#pragma unroll
            for (int i = 0; i < 4; ++i)
                out2[i] = (out2[i] + relu2(s2[i])) * 0.5f;
        }
        store8v(ll_out + xoff, out2);

#pragma unroll
        for (int i = 0; i < 4; ++i) glacc2[i] = pk_add(glacc2[i], y2[8 + i]);
#pragma unroll
        for (int i = 0; i < 4; ++i) ggacc2[i] = pk_add(ggacc2[i], y2[12 + i]);

        float lr = merge3v(y2 + 4, lane);    // ch 8-15 -> lg
        atomicAdd(&s_lg[k][lane & 7], lr);

        xv = xnext;
    }
    {
        const float invU = 1.f / 16.f;
        float4* gp = reinterpret_cast<float4*>(
            gl_out + (((size_t)uz * NB + b) * NA + a) * 8);
        gp[0] = make_float4(glacc2[0].x*invU, glacc2[0].y*invU, glacc2[1].x*invU, glacc2[1].y*invU);
        gp[1] = make_float4(glacc2[2].x*invU, glacc2[2].y*invU, glacc2[3].x*invU, glacc2[3].y*invU);
    }
    float gr = merge3v(ggacc2, lane);
    atomicAdd(&s_gg[lane & 7], gr);
    __syncthreads();
    if (tid < UN * 8)
        atomicAdd(lg_out + ((size_t)b * NU + uz * UN + (tid >> 3)) * 8 + (tid & 7),
                  s_lg[tid >> 3][tid & 7]);
    if (tid >= 64 && tid < 72)
        atomicAdd(gg_out + b * 8 + (tid & 7), s_gg[tid & 7]);
}

// ---------------- Layer 8: out[b,a] = pi * (mean_u f·W8 + b8) ----------------
// z-split partials accumulate via atomicAdd into a zeroed output.
template <int NZ>
__global__ __launch_bounds__(128) void layer_out_t(
    const unsigned short* __restrict__ ll,   // f7' ll (skip already applied)
    const float* __restrict__ lg7, const float* __restrict__ lg3,  // raw sums
    const float* __restrict__ gl7, const float* __restrict__ gl3,  // partial means
    const float* __restrict__ gg7, const float* __restrict__ gg3,  // raw sums
    const float* __restrict__ W8, const float* __restrict__ b8,
    float* __restrict__ out)
{
    constexpr int UN = NU / NZ;
    const int b = blockIdx.x;
    const int a = blockIdx.y * 128 + threadIdx.x;
    const int uz = blockIdx.z;
    const float invA = 1.f / 1024.f, invUA = 1.f / 16384.f, invU = 1.f / 16.f;

    float acc = 0.f;
#pragma unroll
    for (int k = 0; k < UN; ++k) {
        const int u = uz * UN + k;
        float x[8];
        unpack8(*reinterpret_cast<const uint4*>(
            ll + (((size_t)(b * NU + u)) * NA + a) * 8), x);
#pragma unroll
        for (int c = 0; c < 8; ++c) acc += x[c] * W8[c];
    }
    acc *= invU;

    if (uz == 0) {
        float sb = b8[0];
#pragma unroll
        for (int c = 0; c < 8; ++c) {
            float s7 = 0.f, s3 = 0.f;
#pragma unroll
            for (int u = 0; u < NU; ++u) {
                s7 += lg7[(b * NU + u) * 8 + c];
                s3 += lg3[(b * NU + u) * 8 + c];
            }
            sb += ((s7 * invA + s3 * invA) * 0.5f * invU) * W8[8 + c];
        }
#pragma unroll
        for (int c = 0; c < 8; ++c)
            sb += ((gg7[b * 8 + c] + gg3[b * 8 + c]) * invUA * 0.5f) * W8[24 + c];

        float s7[8], s3[8];
#pragma unroll
        for (int i = 0; i < 8; ++i) { s7[i] = 0.f; s3[i] = 0.f; }
#pragma unroll
        for (int z = 0; z < NZ; ++z) {
            const float4* g7 = reinterpret_cast<const float4*>(
                gl7 + (((size_t)z * NB + b) * NA + a) * 8);
            const float4* g3 = reinterpret_cast<const float4*>(
                gl3 + (((size_t)z * NB + b) * NA + a) * 8);
            float4 a0 = g7[0], a1 = g7[1], b0 = g3[0], b1v = g3[1];
            s7[0] += a0.x; s7[1] += a0.y; s7[2] += a0.z; s7[3] += a0.w;
            s7[4] += a1.x; s7[5] += a1.y; s7[6] += a1.z; s7[7] += a1.w;
            s3[0] += b0.x; s3[1] += b0.y; s3[2] += b0.z; s3[3] += b0.w;
            s3[4] += b1v.x; s3[5] += b1v.y; s3[6] += b1v.z; s3[7] += b1v.w;
        }
#pragma unroll
        for (int i = 0; i < 8; ++i)
            acc += 0.5f * (s7[i] + s3[i]) * W8[16 + i];
        acc += sb;
    }
    atomicAdd(out + (size_t)b * NA + a, acc * PI_F);
}

// ---------------- host ----------------
static constexpr size_t LLsz = (size_t)NB * NU * NA * 8;  // elems
static constexpr size_t GLsz = (size_t)NB * NA * 8;
static constexpr size_t LGsz = (size_t)NB * NU * 8;
static constexpr size_t GGsz = (size_t)NB * 8;

template <int NZ>
static void run_pipeline(const float* channel, const float* W1, const float* b1,
                         const float* Wm, const float* bm, const float* W8,
                         const float* b8, float* out, int out_bytes,
                         void* d_ws, hipStream_t stream)
{
    unsigned short* cur = (unsigned short*)d_ws;        // bf16 ll
    unsigned short* f3s = cur + LLsz;                   // bf16 f3 ll copy
    float* glb = (float*)(f3s + LLsz);                  // 4 bufs x NZ*GL fp32
    float* g0 = glb;
    float* g1 = glb + (size_t)NZ * GLsz;
    float* g2 = glb + (size_t)2 * NZ * GLsz;
    float* g3 = glb + (size_t)3 * NZ * GLsz;
    float* lgb = glb + (size_t)4 * NZ * GLsz;           // 7 x LG
    float* ggb = lgb + 7 * LGsz;                        // 7 x GG
    float* base = ggb + 7 * GGsz;                       // 2048 x 32

    hipMemsetAsync(lgb, 0, (7 * LGsz + 7 * GGsz) * sizeof(float), stream);
    hipMemsetAsync(out, 0, out_bytes, stream);

    dim3 grid(NB, NA / 128, NZ), blk(128);

    // L1: f1 -> cur, g0, lgb0, ggb0
    layer_first_t<NZ><<<grid, blk, 0, stream>>>(channel, W1, b1, cur, lgb, g0, ggb);

    // L2: cur -> cur (in-place), g0 -> g2
    prep_base_k<<<8, 256, 0, stream>>>(lgb, nullptr, ggb, nullptr, Wm, bm, base);
    layer_main_t<NZ><<<grid, blk, 0, stream>>>(cur, g0, nullptr, base, Wm,
        nullptr, nullptr, nullptr, nullptr,
        cur, lgb + 1 * LGsz, g2, ggb + 1 * GGsz);

    // L3: cur -> f3s (pinned f3 copy), g2 -> g1
    prep_base_k<<<8, 256, 0, stream>>>(lgb + 1 * LGsz, nullptr, ggb + 1 * GGsz, nullptr,
                                       Wm + 1024, bm + 32, base);
    layer_main_t<NZ><<<grid, blk, 0, stream>>>(cur, g2, nullptr, base, Wm + 1024,
        nullptr, nullptr, nullptr, nullptr,
        f3s, lgb + 2 * LGsz, g1, ggb + 2 * GGsz);

    // L4: f3s -> cur, g1 -> g3
    prep_base_k<<<8, 256, 0, stream>>>(lgb + 2 * LGsz, nullptr, ggb + 2 * GGsz, nullptr,
                                       Wm + 2048, bm + 64, base);
    layer_main_t<NZ><<<grid, blk, 0, stream>>>(f3s, g1, nullptr, base, Wm + 2048,
        nullptr, nullptr, nullptr, nullptr,
        cur, lgb + 3 * LGsz, g3, ggb + 3 * GGsz);

    // L5: cur -> cur, g3 -> g2; ll-skip = recomputed f1 from channel
    prep_base_k<<<8, 256, 0, stream>>>(lgb + 3 * LGsz, nullptr, ggb + 3 * GGsz, nullptr,
                                       Wm + 3072, bm + 96, base);
    layer_main_t<NZ><<<grid, blk, 0, stream>>>(cur, g3, nullptr, base, Wm + 3072,
        nullptr, channel, W1, b1,
        cur, lgb + 4 * LGsz, g2, ggb + 4 * GGsz);

    // L6: cur -> cur, g2 -> g3; input-side skip with f1 factors (lgb0/ggb0/g0)
    prep_base_k<<<8, 256, 0, stream>>>(lgb + 4 * LGsz, lgb, ggb + 4 * GGsz, ggb,
                                       Wm + 4096, bm + 128, base);
    layer_main_t<NZ><<<grid, blk, 0, stream>>>(cur, g2, g0, base, Wm + 4096,
        nullptr, nullptr, nullptr, nullptr,
        cur, lgb + 5 * LGsz, g3, ggb + 5 * GGsz);

    // L7: cur -> cur, g3 -> g2; ll-skip = f3s
    prep_base_k<<<8, 256, 0, stream>>>(lgb + 5 * LGsz, nullptr, ggb + 5 * GGsz, nullptr,
                                       Wm + 5120, bm + 160, base);
    layer_main_t<NZ><<<grid, blk, 0, stream>>>(cur, g3, nullptr, base, Wm + 5120,
        f3s, nullptr, nullptr, nullptr,
        cur, lgb + 6 * LGsz, g2, ggb + 6 * GGsz);

    // L8
    layer_out_t<NZ><<<grid, blk, 0, stream>>>(cur, lgb + 6 * LGsz, lgb + 2 * LGsz,
                                              g2, g1, ggb + 6 * GGsz, ggb + 2 * GGsz,
                                              W8, b8, out);
}

static size_t ws_req(int nz) {
    return LLsz * 2 * sizeof(unsigned short)            // cur + f3s (bf16)
         + (size_t)4 * nz * GLsz * sizeof(float)
         + (7 * LGsz + 7 * GGsz + 2048 * 32) * sizeof(float);
}

extern "C" void kernel_launch(void* const* d_in, const int* in_sizes, int n_in,
                              void* d_out, int out_size, void* d_ws, size_t ws_size,
                              hipStream_t stream) {
    const float* channel = (const float*)d_in[0];
    const float* W1 = (const float*)d_in[1];
    const float* b1 = (const float*)d_in[2];
    const float* Wm = (const float*)d_in[3];
    const float* bm = (const float*)d_in[4];
    const float* W8 = (const float*)d_in[5];
    const float* b8 = (const float*)d_in[6];
    float* out = (float*)d_out;

    if (ws_size >= ws_req(4)) {
        run_pipeline<4>(channel, W1, b1, Wm, bm, W8, b8, out, out_size, d_ws, stream);
    } else if (ws_size >= ws_req(2)) {
        run_pipeline<2>(channel, W1, b1, Wm, bm, W8, b8, out, out_size, d_ws, stream);
    } else {
        run_pipeline<1>(channel, W1, b1, Wm, bm, W8, b8, out, out_size, d_ws, stream);
    }
}